// Round 6
// baseline (172.024 us; speedup 1.0000x reference)
//
#include <hip/hip_runtime.h>
#include <hip/hip_bf16.h>

#define S_LEN 2048
#define BATCH 2
#define DMODEL 1024
#define NHEAD 16
#define HDIM 64
#define MTOT (S_LEN * BATCH)
#define QKV_ELEMS ((size_t)MTOT * DMODEL)

typedef __bf16 bf16x8 __attribute__((ext_vector_type(8)));
typedef unsigned short u16x8 __attribute__((ext_vector_type(8)));
typedef float f32x4 __attribute__((ext_vector_type(4)));
typedef float f32x16 __attribute__((ext_vector_type(16)));
typedef unsigned int u32x4 __attribute__((ext_vector_type(4)));

__device__ __forceinline__ unsigned short f2bf(float f) {
    unsigned int u = __float_as_uint(f);
    u += 0x7FFFu + ((u >> 16) & 1u);
    return (unsigned short)(u >> 16);
}

__device__ __forceinline__ void gload_lds16(const void* g, void* l) {
    __builtin_amdgcn_global_load_lds(
        (const __attribute__((address_space(1))) unsigned int*)g,
        (__attribute__((address_space(3))) unsigned int*)l, 16, 0, 0);
}

// ---------------------------------------------------------------------------
// Projection GEMM: x @ W^T + b, bf16 out. Reg-prefetch pipeline (T14):
//   [convert+write k][barrier][issue loads k+1][compute k][barrier]
// Q: [b][h][s][d] scaled by 0.125*log2(e).  K: [b][h][s][d].  V: [b][h][d][s].
// ---------------------------------------------------------------------------
#define PBM 128
#define PBN 128
#define PBK 32
#define PLDS 48
#define QSCALE 0.18033688011112042f   // 0.125 * log2(e)

__global__ __launch_bounds__(256) void proj_kernel(
        const float* __restrict__ Xq, const float* __restrict__ Xk,
        const float* __restrict__ Xv, const float* __restrict__ Wq,
        const float* __restrict__ Wk, const float* __restrict__ Wv,
        const float* __restrict__ bq, const float* __restrict__ bk,
        const float* __restrict__ bv, unsigned short* __restrict__ ws)
{
    const int t = blockIdx.z;
    const float* X    = (t == 0) ? Xq : (t == 1) ? Xk : Xv;
    const float* W    = (t == 0) ? Wq : (t == 1) ? Wk : Wv;
    const float* bias = (t == 0) ? bq : (t == 1) ? bk : bv;
    unsigned short* out = ws + (size_t)t * QKV_ELEMS;
    const float scale = (t == 0) ? QSCALE : 1.0f;

    __shared__ __align__(16) unsigned short lds[(PBM + PBN) * PLDS];
    unsigned short* Alds = lds;
    unsigned short* Blds = lds + PBM * PLDS;

    const int tid = threadIdx.x;
    const int m0 = blockIdx.y * PBM;
    const int n0 = blockIdx.x * PBN;

    const int wave = tid >> 6;
    const int lane = tid & 63;
    const int lrow = lane & 15;
    const int lg   = lane >> 4;
    const int wr = (wave >> 1) * 64;
    const int wc = (wave & 1) * 64;

    f32x4 acc[4][4];
#pragma unroll
    for (int i = 0; i < 4; ++i)
#pragma unroll
        for (int j = 0; j < 4; ++j)
            acc[i][j] = (f32x4){0.f, 0.f, 0.f, 0.f};

    const int sr = tid >> 3;
    const int sg = tid & 7;

    float4 a_r[4], b_r[4];
#pragma unroll
    for (int it = 0; it < 4; ++it) {
        const int row = sr + it * 32;
        a_r[it] = *(const float4*)(X + (size_t)(m0 + row) * DMODEL + sg * 4);
        b_r[it] = *(const float4*)(W + (size_t)(n0 + row) * DMODEL + sg * 4);
    }

    for (int k0 = 0; k0 < DMODEL; k0 += PBK) {
        // convert + write current tile (regs loaded during previous compute)
#pragma unroll
        for (int it = 0; it < 4; ++it) {
            const int row = sr + it * 32;
            ushort4 ha, hb;
            ha.x = f2bf(a_r[it].x); ha.y = f2bf(a_r[it].y);
            ha.z = f2bf(a_r[it].z); ha.w = f2bf(a_r[it].w);
            hb.x = f2bf(b_r[it].x); hb.y = f2bf(b_r[it].y);
            hb.z = f2bf(b_r[it].z); hb.w = f2bf(b_r[it].w);
            *(ushort4*)&Alds[row * PLDS + sg * 4] = ha;
            *(ushort4*)&Blds[row * PLDS + sg * 4] = hb;
        }
        __syncthreads();

        // issue next tile's global loads (latency hides under compute)
        if (k0 + PBK < DMODEL) {
#pragma unroll
            for (int it = 0; it < 4; ++it) {
                const int row = sr + it * 32;
                a_r[it] = *(const float4*)(X + (size_t)(m0 + row) * DMODEL + k0 + PBK + sg * 4);
                b_r[it] = *(const float4*)(W + (size_t)(n0 + row) * DMODEL + k0 + PBK + sg * 4);
            }
        }

        bf16x8 af[4], bw[4];
#pragma unroll
        for (int i = 0; i < 4; ++i) {
            af[i] = *(const bf16x8*)&Alds[(wr + i * 16 + lrow) * PLDS + lg * 8];
            bw[i] = *(const bf16x8*)&Blds[(wc + i * 16 + lrow) * PLDS + lg * 8];
        }
#pragma unroll
        for (int i = 0; i < 4; ++i)
#pragma unroll
            for (int j = 0; j < 4; ++j)
                acc[i][j] = __builtin_amdgcn_mfma_f32_16x16x32_bf16(af[i], bw[j], acc[i][j], 0, 0, 0);

        __syncthreads();   // protect LDS before next overwrite
    }

#pragma unroll
    for (int j = 0; j < 4; ++j) {
        const int n  = n0 + wc + j * 16 + lrow;
        const float bv_ = bias[n];
        const int h  = n >> 6;
        const int dd = n & 63;
#pragma unroll
        for (int i = 0; i < 4; ++i) {
#pragma unroll
            for (int r = 0; r < 4; ++r) {
                const int m = m0 + wr + i * 16 + lg * 4 + r;
                const int s = m >> 1;
                const int b = m & 1;
                const float v = (acc[i][j][r] + bv_) * scale;
                size_t idx;
                if (t == 2)
                    idx = ((size_t)((b * NHEAD + h) * HDIM + dd)) * S_LEN + s;
                else
                    idx = ((size_t)((b * NHEAD + h) * S_LEN + s)) * HDIM + dd;
                out[idx] = f2bf(v);
            }
        }
    }
}

// ---------------------------------------------------------------------------
// Flash attention, swapped-QK^T 32x32, R3 grid (256 blocks x 512 thr, 8 waves
// share one K/V stage) + dbuf/gload_lds 1-barrier pipeline + in-reg softmax
// (defer-max THR=8, tree reductions) + setprio around MFMA clusters.
// P via per-wave LDS roundtrip, slot->key map identical to V (layout-inv).
// ---------------------------------------------------------------------------
#define NT (S_LEN / 64)

__global__ __launch_bounds__(512) void attn_kernel(
        const unsigned short* __restrict__ ws, float* __restrict__ out)
{
    const unsigned short* Qw = ws;
    const unsigned short* Kw = ws + QKV_ELEMS;
    const unsigned short* Vw = ws + 2 * QKV_ELEMS;   // [b][h][d][s]

    const int bid = blockIdx.x;
    const int idx = bid >> 3;
    const int bh  = (bid & 7) * 4 + (idx >> 3);      // 4 bh per XCD
    const int q0  = (idx & 7) * 256;

    __shared__ __align__(16) unsigned short Kbuf[2][64 * 64];
    __shared__ __align__(16) unsigned short Vbuf[2][64 * 64];
    __shared__ unsigned int Pu[8][32 * 32];          // per-wave [keypair][q]

    const int tid  = threadIdx.x;
    const int wave = tid >> 6;
    const int lane = tid & 63;
    const int l31  = lane & 31;
    const int half = lane >> 5;

    const size_t base = (size_t)bh * S_LEN * HDIM;
    const int qrow = q0 + wave * 32 + l31;

    // Q^T B-fragments: lane covers q = l31, d = c*16 + half*8 + j
    bf16x8 qf[4];
#pragma unroll
    for (int c = 0; c < 4; ++c)
        qf[c] = *(const bf16x8*)(Qw + base + (size_t)qrow * HDIM + c * 16 + half * 8);

    f32x16 Od0, Od1;
#pragma unroll
    for (int i = 0; i < 16; ++i) { Od0[i] = 0.f; Od1[i] = 0.f; }
    float mrun = -__builtin_inff();
    float lrun = 0.f;

    // staging coords: 512 threads cover the 64x64 tile, one 16B gload each
    const int srow = tid >> 3;                 // 0..63
    const int sgrp = (tid & 7) ^ (srow & 7);   // XOR-swizzled source group
    const int dsto = tid * 8;                  // ushort elems (= wave*1024B + lane*16B)

    // prologue: stage tile 0 into buf 0
    gload_lds16(Kw + base + (size_t)srow * HDIM + sgrp * 8,  &Kbuf[0][dsto]);
    gload_lds16(Vw + base + (size_t)srow * S_LEN + sgrp * 8, &Vbuf[0][dsto]);
    __syncthreads();

    int cur = 0;
    for (int t = 0; t < NT; ++t) {
        // stage next tile into buf[cur^1] (in flight across this tile)
        if (t + 1 < NT) {
            const int sn = (t + 1) * 64;
            gload_lds16(Kw + base + (size_t)(sn + srow) * HDIM + sgrp * 8, &Kbuf[cur ^ 1][dsto]);
            gload_lds16(Vw + base + (size_t)srow * S_LEN + sn + sgrp * 8, &Vbuf[cur ^ 1][dsto]);
        }

        const unsigned short* Klds = Kbuf[cur];
        const unsigned short* Vlds = Vbuf[cur];

        // S^T = K . Q^T (two 32-key tiles); A and B share the slot->k map.
        f32x16 S0, S1;
#pragma unroll
        for (int i = 0; i < 16; ++i) { S0[i] = 0.f; S1[i] = 0.f; }
        __builtin_amdgcn_s_setprio(1);
#pragma unroll
        for (int c = 0; c < 4; ++c) {
            const int g = ((c * 2 + half) ^ (l31 & 7)) * 8;
            const bf16x8 ka0 = *(const bf16x8*)&Klds[l31 * 64 + g];
            const bf16x8 ka1 = *(const bf16x8*)&Klds[(32 + l31) * 64 + g];
            S0 = __builtin_amdgcn_mfma_f32_32x32x16_bf16(ka0, qf[c], S0, 0, 0, 0);
            S1 = __builtin_amdgcn_mfma_f32_32x32x16_bf16(ka1, qf[c], S1, 0, 0, 0);
        }
        __builtin_amdgcn_s_setprio(0);

        // ---- in-register online softmax (base 2), defer-max THR=8 ----
        f32x16 mx16;
#pragma unroll
        for (int i = 0; i < 16; ++i) mx16[i] = fmaxf(S0[i], S1[i]);
        float m8[8], m4[4], m2[2];
#pragma unroll
        for (int i = 0; i < 8; ++i) m8[i] = fmaxf(mx16[i], mx16[i + 8]);
#pragma unroll
        for (int i = 0; i < 4; ++i) m4[i] = fmaxf(m8[i], m8[i + 4]);
        m2[0] = fmaxf(m4[0], m4[2]); m2[1] = fmaxf(m4[1], m4[3]);
        float mx = fmaxf(m2[0], m2[1]);
        mx = fmaxf(mx, __shfl_xor(mx, 32, 64));

        if (!__all(mx - mrun <= 8.0f)) {
            const float mnew = fmaxf(mrun, mx);
            const float ex   = exp2f(mrun - mnew);
            mrun = mnew;
            lrun *= ex;
            Od0 *= ex;
            Od1 *= ex;
        }

#pragma unroll
        for (int i = 0; i < 16; ++i) S0[i] = exp2f(S0[i] - mrun);
#pragma unroll
        for (int i = 0; i < 16; ++i) S1[i] = exp2f(S1[i] - mrun);
        f32x16 sv = S0 + S1;
        float s8[8], s4[4];
#pragma unroll
        for (int i = 0; i < 8; ++i) s8[i] = sv[i] + sv[i + 8];
#pragma unroll
        for (int i = 0; i < 4; ++i) s4[i] = s8[i] + s8[i + 4];
        float psum = (s4[0] + s4[2]) + (s4[1] + s4[3]);
        psum += __shfl_xor(psum, 32, 64);
        lrun += psum;

        // ---- P^T -> per-wave LDS as packed key-pairs (C/D layout m74/m101) ----
#pragma unroll
        for (int w = 0; w < 8; ++w) {
            const unsigned int pk0 = (unsigned int)f2bf(S0[2 * w])
                                   | ((unsigned int)f2bf(S0[2 * w + 1]) << 16);
            const unsigned int pk1 = (unsigned int)f2bf(S1[2 * w])
                                   | ((unsigned int)f2bf(S1[2 * w + 1]) << 16);
            const int kp = (w & 1) + 4 * (w >> 1) + 2 * half;
            Pu[wave][kp * 32 + l31]        = pk0;
            Pu[wave][(16 + kp) * 32 + l31] = pk1;
        }
        __asm__ volatile("" ::: "memory");

        // ---- PV: O^T[d][q] += V^T . P^T (same slot->key map as V frags) ----
        __builtin_amdgcn_s_setprio(1);
#pragma unroll
        for (int c = 0; c < 4; ++c) {
            const int g = ((c * 2 + half) ^ (l31 & 7)) * 8;
            const bf16x8 va0 = *(const bf16x8*)&Vlds[l31 * 64 + g];
            const bf16x8 va1 = *(const bf16x8*)&Vlds[(32 + l31) * 64 + g];
            u32x4 pu;
#pragma unroll
            for (int e = 0; e < 4; ++e)
                pu[e] = Pu[wave][(c * 8 + half * 4 + e) * 32 + l31];
            const bf16x8 pb = __builtin_bit_cast(bf16x8, pu);
            Od0 = __builtin_amdgcn_mfma_f32_32x32x16_bf16(va0, pb, Od0, 0, 0, 0);
            Od1 = __builtin_amdgcn_mfma_f32_32x32x16_bf16(va1, pb, Od1, 0, 0, 0);
        }
        __builtin_amdgcn_s_setprio(0);

        __syncthreads();   // drains stage loads + orders buffer swap
        cur ^= 1;
    }

    // epilogue: normalize, write fp32 out[s][b][h*64+d]
    const int bb = bh >> 4;
    const int hh = bh & 15;
    const float inv = 1.0f / lrun;
    float* op = out + (size_t)qrow * (BATCH * DMODEL) + bb * DMODEL + hh * HDIM;
#pragma unroll
    for (int gg = 0; gg < 4; ++gg) {
        const int d0 = gg * 8 + half * 4;
        float4 v0, v1;
        v0.x = Od0[gg * 4 + 0] * inv; v0.y = Od0[gg * 4 + 1] * inv;
        v0.z = Od0[gg * 4 + 2] * inv; v0.w = Od0[gg * 4 + 3] * inv;
        v1.x = Od1[gg * 4 + 0] * inv; v1.y = Od1[gg * 4 + 1] * inv;
        v1.z = Od1[gg * 4 + 2] * inv; v1.w = Od1[gg * 4 + 3] * inv;
        *(float4*)(op + d0)      = v0;
        *(float4*)(op + 32 + d0) = v1;
    }
}

extern "C" void kernel_launch(void* const* d_in, const int* in_sizes, int n_in,
                              void* d_out, int out_size, void* d_ws, size_t ws_size,
                              hipStream_t stream) {
    const float* q  = (const float*)d_in[0];
    const float* k  = (const float*)d_in[1];
    const float* v  = (const float*)d_in[2];
    const float* Wq = (const float*)d_in[3];
    const float* bq = (const float*)d_in[4];
    const float* Wk = (const float*)d_in[5];
    const float* bk = (const float*)d_in[6];
    const float* Wv = (const float*)d_in[7];
    const float* bv = (const float*)d_in[8];
    unsigned short* ws = (unsigned short*)d_ws;
    float* out = (float*)d_out;

    dim3 pgrid(DMODEL / PBN, MTOT / PBM, 3);
    proj_kernel<<<pgrid, dim3(256), 0, stream>>>(q, k, v, Wq, Wk, Wv, bq, bk, bv, ws);

    attn_kernel<<<dim3(256), dim3(512), 0, stream>>>(ws, out);
}

// Round 7
// 153.165 us; speedup vs baseline: 1.1231x; 1.1231x over previous
//
#include <hip/hip_runtime.h>
#include <hip/hip_bf16.h>

#define S_LEN 2048
#define BATCH 2
#define DMODEL 1024
#define NHEAD 16
#define HDIM 64
#define MTOT (S_LEN * BATCH)
#define QKV_ELEMS ((size_t)MTOT * DMODEL)

typedef __bf16 bf16x8 __attribute__((ext_vector_type(8)));
typedef unsigned short u16x8 __attribute__((ext_vector_type(8)));
typedef float f32x4 __attribute__((ext_vector_type(4)));
typedef float f32x16 __attribute__((ext_vector_type(16)));
typedef unsigned int u32x4 __attribute__((ext_vector_type(4)));

__device__ __forceinline__ unsigned short f2bf(float f) {
    unsigned int u = __float_as_uint(f);
    u += 0x7FFFu + ((u >> 16) & 1u);
    return (unsigned short)(u >> 16);
}

__device__ __forceinline__ void gload_lds16(const void* g, void* l) {
    __builtin_amdgcn_global_load_lds(
        (const __attribute__((address_space(1))) unsigned int*)g,
        (__attribute__((address_space(3))) unsigned int*)l, 16, 0, 0);
}

// ---------------------------------------------------------------------------
// Projection GEMM: x @ W^T + b, bf16 out.  Staging loop = verified R1-R3 form
// (T14 prefetch reverted: regalloc blowup, -2x).  Linear grid + chunked XCD
// swizzle (m157): each XCD owns 96 contiguous (t,m,n) blocks -> X/W panels
// stay L2-resident (fetch-bound fix).
// Q: [b][h][s][d] scaled by 0.125*log2(e).  K: [b][h][s][d].  V: [b][h][d][s].
// ---------------------------------------------------------------------------
#define PBM 128
#define PBN 128
#define PBK 32
#define PLDS 48
#define QSCALE 0.18033688011112042f   // 0.125 * log2(e)

__global__ __launch_bounds__(256) void proj_kernel(
        const float* __restrict__ Xq, const float* __restrict__ Xk,
        const float* __restrict__ Xv, const float* __restrict__ Wq,
        const float* __restrict__ Wk, const float* __restrict__ Wv,
        const float* __restrict__ bq, const float* __restrict__ bk,
        const float* __restrict__ bv, unsigned short* __restrict__ ws)
{
    // chunked XCD swizzle: HW round-robins bid->XCD, so work (bid&7)*96+(bid>>3)
    // gives XCD x the contiguous work-chunk [96x, 96x+96).
    const int work = (blockIdx.x & 7) * 96 + (blockIdx.x >> 3);   // 0..767
    const int t    = work >> 8;           // tensor 0..2
    const int rem  = work & 255;
    const int m0   = (rem >> 3) * PBM;    // 32 m-blocks
    const int n0   = (rem & 7) * PBN;     // 8 n-blocks

    const float* X    = (t == 0) ? Xq : (t == 1) ? Xk : Xv;
    const float* W    = (t == 0) ? Wq : (t == 1) ? Wk : Wv;
    const float* bias = (t == 0) ? bq : (t == 1) ? bk : bv;
    unsigned short* out = ws + (size_t)t * QKV_ELEMS;
    const float scale = (t == 0) ? QSCALE : 1.0f;

    __shared__ __align__(16) unsigned short lds[(PBM + PBN) * PLDS];
    unsigned short* Alds = lds;
    unsigned short* Blds = lds + PBM * PLDS;

    const int tid = threadIdx.x;
    const int wave = tid >> 6;
    const int lane = tid & 63;
    const int lrow = lane & 15;
    const int lg   = lane >> 4;
    const int wr = (wave >> 1) * 64;
    const int wc = (wave & 1) * 64;

    f32x4 acc[4][4];
#pragma unroll
    for (int i = 0; i < 4; ++i)
#pragma unroll
        for (int j = 0; j < 4; ++j)
            acc[i][j] = (f32x4){0.f, 0.f, 0.f, 0.f};

    const int sr = tid >> 3;
    const int sg = tid & 7;

    for (int k0 = 0; k0 < DMODEL; k0 += PBK) {
        __syncthreads();
#pragma unroll
        for (int it = 0; it < 4; ++it) {
            const int row = sr + it * 32;
            const float4 va = *(const float4*)(X + (size_t)(m0 + row) * DMODEL + k0 + sg * 4);
            const float4 vb = *(const float4*)(W + (size_t)(n0 + row) * DMODEL + k0 + sg * 4);
            ushort4 ha, hb;
            ha.x = f2bf(va.x); ha.y = f2bf(va.y); ha.z = f2bf(va.z); ha.w = f2bf(va.w);
            hb.x = f2bf(vb.x); hb.y = f2bf(vb.y); hb.z = f2bf(vb.z); hb.w = f2bf(vb.w);
            *(ushort4*)&Alds[row * PLDS + sg * 4] = ha;
            *(ushort4*)&Blds[row * PLDS + sg * 4] = hb;
        }
        __syncthreads();

        bf16x8 af[4], bw[4];
#pragma unroll
        for (int i = 0; i < 4; ++i) {
            af[i] = *(const bf16x8*)&Alds[(wr + i * 16 + lrow) * PLDS + lg * 8];
            bw[i] = *(const bf16x8*)&Blds[(wc + i * 16 + lrow) * PLDS + lg * 8];
        }
#pragma unroll
        for (int i = 0; i < 4; ++i)
#pragma unroll
            for (int j = 0; j < 4; ++j)
                acc[i][j] = __builtin_amdgcn_mfma_f32_16x16x32_bf16(af[i], bw[j], acc[i][j], 0, 0, 0);
    }

#pragma unroll
    for (int j = 0; j < 4; ++j) {
        const int n  = n0 + wc + j * 16 + lrow;
        const float bv_ = bias[n];
        const int h  = n >> 6;
        const int dd = n & 63;
#pragma unroll
        for (int i = 0; i < 4; ++i) {
#pragma unroll
            for (int r = 0; r < 4; ++r) {
                const int m = m0 + wr + i * 16 + lg * 4 + r;
                const int s = m >> 1;
                const int b = m & 1;
                const float v = (acc[i][j][r] + bv_) * scale;
                size_t idx;
                if (t == 2)
                    idx = ((size_t)((b * NHEAD + h) * HDIM + dd)) * S_LEN + s;
                else
                    idx = ((size_t)((b * NHEAD + h) * S_LEN + s)) * HDIM + dd;
                out[idx] = f2bf(v);
            }
        }
    }
}

// ---------------------------------------------------------------------------
// Flash attention (unchanged from R5 — verified ~59 us): swapped-QK^T 32x32,
// 256 blocks x 512 thr, shared K/V stage, dbuf + gload_lds 1-barrier pipeline,
// in-reg softmax (defer-max THR=8), P via per-wave LDS (layout-invariant).
// ---------------------------------------------------------------------------
#define NT (S_LEN / 64)

__global__ __launch_bounds__(512) void attn_kernel(
        const unsigned short* __restrict__ ws, float* __restrict__ out)
{
    const unsigned short* Qw = ws;
    const unsigned short* Kw = ws + QKV_ELEMS;
    const unsigned short* Vw = ws + 2 * QKV_ELEMS;   // [b][h][d][s]

    const int bid = blockIdx.x;
    const int idx = bid >> 3;
    const int bh  = (bid & 7) * 4 + (idx >> 3);      // 4 bh per XCD
    const int q0  = (idx & 7) * 256;

    __shared__ __align__(16) unsigned short Kbuf[2][64 * 64];
    __shared__ __align__(16) unsigned short Vbuf[2][64 * 64];
    __shared__ unsigned int Pu[8][32 * 32];          // per-wave [keypair][q]

    const int tid  = threadIdx.x;
    const int wave = tid >> 6;
    const int lane = tid & 63;
    const int l31  = lane & 31;
    const int half = lane >> 5;

    const size_t base = (size_t)bh * S_LEN * HDIM;
    const int qrow = q0 + wave * 32 + l31;

    bf16x8 qf[4];
#pragma unroll
    for (int c = 0; c < 4; ++c)
        qf[c] = *(const bf16x8*)(Qw + base + (size_t)qrow * HDIM + c * 16 + half * 8);

    f32x16 Od0, Od1;
#pragma unroll
    for (int i = 0; i < 16; ++i) { Od0[i] = 0.f; Od1[i] = 0.f; }
    float mrun = -__builtin_inff();
    float lrun = 0.f;

    const int srow = tid >> 3;                 // 0..63
    const int sgrp = (tid & 7) ^ (srow & 7);   // XOR-swizzled source group
    const int dsto = tid * 8;

    gload_lds16(Kw + base + (size_t)srow * HDIM + sgrp * 8,  &Kbuf[0][dsto]);
    gload_lds16(Vw + base + (size_t)srow * S_LEN + sgrp * 8, &Vbuf[0][dsto]);
    __syncthreads();

    int cur = 0;
    for (int t = 0; t < NT; ++t) {
        if (t + 1 < NT) {
            const int sn = (t + 1) * 64;
            gload_lds16(Kw + base + (size_t)(sn + srow) * HDIM + sgrp * 8, &Kbuf[cur ^ 1][dsto]);
            gload_lds16(Vw + base + (size_t)srow * S_LEN + sn + sgrp * 8, &Vbuf[cur ^ 1][dsto]);
        }

        const unsigned short* Klds = Kbuf[cur];
        const unsigned short* Vlds = Vbuf[cur];

        f32x16 S0, S1;
#pragma unroll
        for (int i = 0; i < 16; ++i) { S0[i] = 0.f; S1[i] = 0.f; }
        __builtin_amdgcn_s_setprio(1);
#pragma unroll
        for (int c = 0; c < 4; ++c) {
            const int g = ((c * 2 + half) ^ (l31 & 7)) * 8;
            const bf16x8 ka0 = *(const bf16x8*)&Klds[l31 * 64 + g];
            const bf16x8 ka1 = *(const bf16x8*)&Klds[(32 + l31) * 64 + g];
            S0 = __builtin_amdgcn_mfma_f32_32x32x16_bf16(ka0, qf[c], S0, 0, 0, 0);
            S1 = __builtin_amdgcn_mfma_f32_32x32x16_bf16(ka1, qf[c], S1, 0, 0, 0);
        }
        __builtin_amdgcn_s_setprio(0);

        f32x16 mx16;
#pragma unroll
        for (int i = 0; i < 16; ++i) mx16[i] = fmaxf(S0[i], S1[i]);
        float m8[8], m4[4], m2[2];
#pragma unroll
        for (int i = 0; i < 8; ++i) m8[i] = fmaxf(mx16[i], mx16[i + 8]);
#pragma unroll
        for (int i = 0; i < 4; ++i) m4[i] = fmaxf(m8[i], m8[i + 4]);
        m2[0] = fmaxf(m4[0], m4[2]); m2[1] = fmaxf(m4[1], m4[3]);
        float mx = fmaxf(m2[0], m2[1]);
        mx = fmaxf(mx, __shfl_xor(mx, 32, 64));

        if (!__all(mx - mrun <= 8.0f)) {
            const float mnew = fmaxf(mrun, mx);
            const float ex   = exp2f(mrun - mnew);
            mrun = mnew;
            lrun *= ex;
            Od0 *= ex;
            Od1 *= ex;
        }

#pragma unroll
        for (int i = 0; i < 16; ++i) S0[i] = exp2f(S0[i] - mrun);
#pragma unroll
        for (int i = 0; i < 16; ++i) S1[i] = exp2f(S1[i] - mrun);
        f32x16 sv = S0 + S1;
        float s8[8], s4[4];
#pragma unroll
        for (int i = 0; i < 8; ++i) s8[i] = sv[i] + sv[i + 8];
#pragma unroll
        for (int i = 0; i < 4; ++i) s4[i] = s8[i] + s8[i + 4];
        float psum = (s4[0] + s4[2]) + (s4[1] + s4[3]);
        psum += __shfl_xor(psum, 32, 64);
        lrun += psum;

#pragma unroll
        for (int w = 0; w < 8; ++w) {
            const unsigned int pk0 = (unsigned int)f2bf(S0[2 * w])
                                   | ((unsigned int)f2bf(S0[2 * w + 1]) << 16);
            const unsigned int pk1 = (unsigned int)f2bf(S1[2 * w])
                                   | ((unsigned int)f2bf(S1[2 * w + 1]) << 16);
            const int kp = (w & 1) + 4 * (w >> 1) + 2 * half;
            Pu[wave][kp * 32 + l31]        = pk0;
            Pu[wave][(16 + kp) * 32 + l31] = pk1;
        }
        __asm__ volatile("" ::: "memory");

        __builtin_amdgcn_s_setprio(1);
#pragma unroll
        for (int c = 0; c < 4; ++c) {
            const int g = ((c * 2 + half) ^ (l31 & 7)) * 8;
            const bf16x8 va0 = *(const bf16x8*)&Vlds[l31 * 64 + g];
            const bf16x8 va1 = *(const bf16x8*)&Vlds[(32 + l31) * 64 + g];
            u32x4 pu;
#pragma unroll
            for (int e = 0; e < 4; ++e)
                pu[e] = Pu[wave][(c * 8 + half * 4 + e) * 32 + l31];
            const bf16x8 pb = __builtin_bit_cast(bf16x8, pu);
            Od0 = __builtin_amdgcn_mfma_f32_32x32x16_bf16(va0, pb, Od0, 0, 0, 0);
            Od1 = __builtin_amdgcn_mfma_f32_32x32x16_bf16(va1, pb, Od1, 0, 0, 0);
        }
        __builtin_amdgcn_s_setprio(0);

        __syncthreads();
        cur ^= 1;
    }

    const int bb = bh >> 4;
    const int hh = bh & 15;
    const float inv = 1.0f / lrun;
    float* op = out + (size_t)qrow * (BATCH * DMODEL) + bb * DMODEL + hh * HDIM;
#pragma unroll
    for (int gg = 0; gg < 4; ++gg) {
        const int d0 = gg * 8 + half * 4;
        float4 v0, v1;
        v0.x = Od0[gg * 4 + 0] * inv; v0.y = Od0[gg * 4 + 1] * inv;
        v0.z = Od0[gg * 4 + 2] * inv; v0.w = Od0[gg * 4 + 3] * inv;
        v1.x = Od1[gg * 4 + 0] * inv; v1.y = Od1[gg * 4 + 1] * inv;
        v1.z = Od1[gg * 4 + 2] * inv; v1.w = Od1[gg * 4 + 3] * inv;
        *(float4*)(op + d0)      = v0;
        *(float4*)(op + 32 + d0) = v1;
    }
}

extern "C" void kernel_launch(void* const* d_in, const int* in_sizes, int n_in,
                              void* d_out, int out_size, void* d_ws, size_t ws_size,
                              hipStream_t stream) {
    const float* q  = (const float*)d_in[0];
    const float* k  = (const float*)d_in[1];
    const float* v  = (const float*)d_in[2];
    const float* Wq = (const float*)d_in[3];
    const float* bq = (const float*)d_in[4];
    const float* Wk = (const float*)d_in[5];
    const float* bk = (const float*)d_in[6];
    const float* Wv = (const float*)d_in[7];
    const float* bv = (const float*)d_in[8];
    unsigned short* ws = (unsigned short*)d_ws;
    float* out = (float*)d_out;

    proj_kernel<<<dim3(768), dim3(256), 0, stream>>>(q, k, v, Wq, Wk, Wv, bq, bk, bv, ws);
    attn_kernel<<<dim3(256), dim3(512), 0, stream>>>(ws, out);
}

// Round 9
// 151.103 us; speedup vs baseline: 1.1385x; 1.0136x over previous
//
#include <hip/hip_runtime.h>
#include <hip/hip_bf16.h>

#define S_LEN 2048
#define BATCH 2
#define DMODEL 1024
#define NHEAD 16
#define HDIM 64
#define MTOT (S_LEN * BATCH)
#define QKV_ELEMS ((size_t)MTOT * DMODEL)

typedef __bf16 bf16x8 __attribute__((ext_vector_type(8)));
typedef unsigned short u16x8 __attribute__((ext_vector_type(8)));
typedef float f32x4 __attribute__((ext_vector_type(4)));
typedef float f32x16 __attribute__((ext_vector_type(16)));
typedef unsigned int u32x4 __attribute__((ext_vector_type(4)));

__device__ __forceinline__ unsigned short f2bf(float f) {
    unsigned int u = __float_as_uint(f);
    u += 0x7FFFu + ((u >> 16) & 1u);
    return (unsigned short)(u >> 16);
}

// compiler-emitted v_cvt_pk_bf16_f32 (m240: do NOT hand-asm this).
// memcpy instead of bit_cast: __hip_bfloat162 is not trivially copyable.
__device__ __forceinline__ unsigned int pack2(float lo, float hi) {
    __hip_bfloat162 h = __float22bfloat162_rn(make_float2(lo, hi));
    unsigned int r;
    __builtin_memcpy(&r, &h, 4);
    return r;
}

__device__ __forceinline__ void gload_lds16(const void* g, void* l) {
    __builtin_amdgcn_global_load_lds(
        (const __attribute__((address_space(1))) unsigned int*)g,
        (__attribute__((address_space(3))) unsigned int*)l, 16, 0, 0);
}

// ---------------------------------------------------------------------------
// Projection GEMM (frozen from R6 — chunked XCD swizzle verified 114->53 us).
// Q: [b][h][s][d] scaled by 0.125*log2(e).  K: [b][h][s][d].  V: [b][h][d][s].
// ---------------------------------------------------------------------------
#define PBM 128
#define PBN 128
#define PBK 32
#define PLDS 48
#define QSCALE 0.18033688011112042f   // 0.125 * log2(e)

__global__ __launch_bounds__(256) void proj_kernel(
        const float* __restrict__ Xq, const float* __restrict__ Xk,
        const float* __restrict__ Xv, const float* __restrict__ Wq,
        const float* __restrict__ Wk, const float* __restrict__ Wv,
        const float* __restrict__ bq, const float* __restrict__ bk,
        const float* __restrict__ bv, unsigned short* __restrict__ ws)
{
    const int work = (blockIdx.x & 7) * 96 + (blockIdx.x >> 3);   // 0..767
    const int t    = work >> 8;
    const int rem  = work & 255;
    const int m0   = (rem >> 3) * PBM;
    const int n0   = (rem & 7) * PBN;

    const float* X    = (t == 0) ? Xq : (t == 1) ? Xk : Xv;
    const float* W    = (t == 0) ? Wq : (t == 1) ? Wk : Wv;
    const float* bias = (t == 0) ? bq : (t == 1) ? bk : bv;
    unsigned short* out = ws + (size_t)t * QKV_ELEMS;
    const float scale = (t == 0) ? QSCALE : 1.0f;

    __shared__ __align__(16) unsigned short lds[(PBM + PBN) * PLDS];
    unsigned short* Alds = lds;
    unsigned short* Blds = lds + PBM * PLDS;

    const int tid = threadIdx.x;
    const int wave = tid >> 6;
    const int lane = tid & 63;
    const int lrow = lane & 15;
    const int lg   = lane >> 4;
    const int wr = (wave >> 1) * 64;
    const int wc = (wave & 1) * 64;

    f32x4 acc[4][4];
#pragma unroll
    for (int i = 0; i < 4; ++i)
#pragma unroll
        for (int j = 0; j < 4; ++j)
            acc[i][j] = (f32x4){0.f, 0.f, 0.f, 0.f};

    const int sr = tid >> 3;
    const int sg = tid & 7;

    for (int k0 = 0; k0 < DMODEL; k0 += PBK) {
        __syncthreads();
#pragma unroll
        for (int it = 0; it < 4; ++it) {
            const int row = sr + it * 32;
            const float4 va = *(const float4*)(X + (size_t)(m0 + row) * DMODEL + k0 + sg * 4);
            const float4 vb = *(const float4*)(W + (size_t)(n0 + row) * DMODEL + k0 + sg * 4);
            ushort4 ha, hb;
            ha.x = f2bf(va.x); ha.y = f2bf(va.y); ha.z = f2bf(va.z); ha.w = f2bf(va.w);
            hb.x = f2bf(vb.x); hb.y = f2bf(vb.y); hb.z = f2bf(vb.z); hb.w = f2bf(vb.w);
            *(ushort4*)&Alds[row * PLDS + sg * 4] = ha;
            *(ushort4*)&Blds[row * PLDS + sg * 4] = hb;
        }
        __syncthreads();

        bf16x8 af[4], bw[4];
#pragma unroll
        for (int i = 0; i < 4; ++i) {
            af[i] = *(const bf16x8*)&Alds[(wr + i * 16 + lrow) * PLDS + lg * 8];
            bw[i] = *(const bf16x8*)&Blds[(wc + i * 16 + lrow) * PLDS + lg * 8];
        }
#pragma unroll
        for (int i = 0; i < 4; ++i)
#pragma unroll
            for (int j = 0; j < 4; ++j)
                acc[i][j] = __builtin_amdgcn_mfma_f32_16x16x32_bf16(af[i], bw[j], acc[i][j], 0, 0, 0);
    }

#pragma unroll
    for (int j = 0; j < 4; ++j) {
        const int n  = n0 + wc + j * 16 + lrow;
        const float bv_ = bias[n];
        const int h  = n >> 6;
        const int dd = n & 63;
#pragma unroll
        for (int i = 0; i < 4; ++i) {
#pragma unroll
            for (int r = 0; r < 4; ++r) {
                const int m = m0 + wr + i * 16 + lg * 4 + r;
                const int s = m >> 1;
                const int b = m & 1;
                const float v = (acc[i][j][r] + bv_) * scale;
                size_t idx;
                if (t == 2)
                    idx = ((size_t)((b * NHEAD + h) * HDIM + dd)) * S_LEN + s;
                else
                    idx = ((size_t)((b * NHEAD + h) * S_LEN + s)) * HDIM + dd;
                out[idx] = f2bf(v);
            }
        }
    }
}

// ---------------------------------------------------------------------------
// Flash attention: swapped-QK^T 32x32, 256 blk x 512 thr, dbuf gload_lds.
// VALU-cut round: cvt_pk packing, ones-MFMA row sums (no sum tree / no sum
// shuffle / no lrun), max3-friendly max tree.
// ---------------------------------------------------------------------------
#define NT (S_LEN / 64)

__global__ __launch_bounds__(512) void attn_kernel(
        const unsigned short* __restrict__ ws, float* __restrict__ out)
{
    const unsigned short* Qw = ws;
    const unsigned short* Kw = ws + QKV_ELEMS;
    const unsigned short* Vw = ws + 2 * QKV_ELEMS;   // [b][h][d][s]

    const int bid = blockIdx.x;
    const int idx = bid >> 3;
    const int bh  = (bid & 7) * 4 + (idx >> 3);      // 4 bh per XCD
    const int q0  = (idx & 7) * 256;

    __shared__ __align__(16) unsigned short Kbuf[2][64 * 64];
    __shared__ __align__(16) unsigned short Vbuf[2][64 * 64];
    __shared__ unsigned int Pu[8][32 * 32];          // per-wave [keypair][q]

    const int tid  = threadIdx.x;
    const int wave = tid >> 6;
    const int lane = tid & 63;
    const int l31  = lane & 31;
    const int half = lane >> 5;

    const size_t base = (size_t)bh * S_LEN * HDIM;
    const int qrow = q0 + wave * 32 + l31;

    bf16x8 qf[4];
#pragma unroll
    for (int c = 0; c < 4; ++c)
        qf[c] = *(const bf16x8*)(Qw + base + (size_t)qrow * HDIM + c * 16 + half * 8);

    // all-ones bf16 A-fragment for row-sum MFMA (layout-invariant)
    bf16x8 ones;
    {
        u16x8 o;
#pragma unroll
        for (int e = 0; e < 8; ++e) o[e] = 0x3F80;
        ones = __builtin_bit_cast(bf16x8, o);
    }

    f32x16 Od0, Od1, Lacc;
#pragma unroll
    for (int i = 0; i < 16; ++i) { Od0[i] = 0.f; Od1[i] = 0.f; Lacc[i] = 0.f; }
    float mrun = -__builtin_inff();

    // hoisted swizzled LDS group offsets (tile-invariant)
    int g_[4];
#pragma unroll
    for (int c = 0; c < 4; ++c) g_[c] = ((c * 2 + half) ^ (l31 & 7)) * 8;

    const int srow = tid >> 3;                 // 0..63
    const int sgrp = (tid & 7) ^ (srow & 7);   // XOR-swizzled source group
    const int dsto = tid * 8;

    gload_lds16(Kw + base + (size_t)srow * HDIM + sgrp * 8,  &Kbuf[0][dsto]);
    gload_lds16(Vw + base + (size_t)srow * S_LEN + sgrp * 8, &Vbuf[0][dsto]);
    __syncthreads();

    int cur = 0;
    for (int t = 0; t < NT; ++t) {
        if (t + 1 < NT) {
            const int sn = (t + 1) * 64;
            gload_lds16(Kw + base + (size_t)(sn + srow) * HDIM + sgrp * 8, &Kbuf[cur ^ 1][dsto]);
            gload_lds16(Vw + base + (size_t)srow * S_LEN + sn + sgrp * 8, &Vbuf[cur ^ 1][dsto]);
        }

        const unsigned short* Klds = Kbuf[cur];
        const unsigned short* Vlds = Vbuf[cur];

        f32x16 S0, S1;
#pragma unroll
        for (int i = 0; i < 16; ++i) { S0[i] = 0.f; S1[i] = 0.f; }
        __builtin_amdgcn_s_setprio(1);
#pragma unroll
        for (int c = 0; c < 4; ++c) {
            const bf16x8 ka0 = *(const bf16x8*)&Klds[l31 * 64 + g_[c]];
            const bf16x8 ka1 = *(const bf16x8*)&Klds[(32 + l31) * 64 + g_[c]];
            S0 = __builtin_amdgcn_mfma_f32_32x32x16_bf16(ka0, qf[c], S0, 0, 0, 0);
            S1 = __builtin_amdgcn_mfma_f32_32x32x16_bf16(ka1, qf[c], S1, 0, 0, 0);
        }
        __builtin_amdgcn_s_setprio(0);

        // ---- max (max3-friendly triplet tree) ----
        float m16[16];
#pragma unroll
        for (int i = 0; i < 16; ++i) m16[i] = fmaxf(S0[i], S1[i]);
        float a0 = fmaxf(fmaxf(m16[0],  m16[1]),  m16[2]);
        float a1 = fmaxf(fmaxf(m16[3],  m16[4]),  m16[5]);
        float a2 = fmaxf(fmaxf(m16[6],  m16[7]),  m16[8]);
        float a3 = fmaxf(fmaxf(m16[9],  m16[10]), m16[11]);
        float a4 = fmaxf(fmaxf(m16[12], m16[13]), m16[14]);
        float b0 = fmaxf(fmaxf(a0, a1), a2);
        float b1 = fmaxf(fmaxf(a3, a4), m16[15]);
        float mx = fmaxf(b0, b1);
        mx = fmaxf(mx, __shfl_xor(mx, 32, 64));

        if (!__all(mx - mrun <= 8.0f)) {         // defer-max THR=8
            const float mnew = fmaxf(mrun, mx);
            const float ex   = exp2f(mrun - mnew);
            mrun = mnew;
            Od0 *= ex;
            Od1 *= ex;
            Lacc *= ex;
        }

#pragma unroll
        for (int i = 0; i < 16; ++i) S0[i] = exp2f(S0[i] - mrun);
#pragma unroll
        for (int i = 0; i < 16; ++i) S1[i] = exp2f(S1[i] - mrun);

        // ---- P^T -> per-wave LDS as packed key-pairs (cvt_pk via compiler) ----
#pragma unroll
        for (int w = 0; w < 8; ++w) {
            const unsigned int pk0 = pack2(S0[2 * w], S0[2 * w + 1]);
            const unsigned int pk1 = pack2(S1[2 * w], S1[2 * w + 1]);
            const int kp = (w & 1) + 4 * (w >> 1) + 2 * half;
            Pu[wave][kp * 32 + l31]        = pk0;
            Pu[wave][(16 + kp) * 32 + l31] = pk1;
        }
        __asm__ volatile("" ::: "memory");

        // ---- PV + ones-row-sum: O^T += V^T.P^T ; Lacc += 1.P^T ----
        __builtin_amdgcn_s_setprio(1);
#pragma unroll
        for (int c = 0; c < 4; ++c) {
            const bf16x8 va0 = *(const bf16x8*)&Vlds[l31 * 64 + g_[c]];
            const bf16x8 va1 = *(const bf16x8*)&Vlds[(32 + l31) * 64 + g_[c]];
            u32x4 pu;
#pragma unroll
            for (int e = 0; e < 4; ++e)
                pu[e] = Pu[wave][(c * 8 + half * 4 + e) * 32 + l31];
            const bf16x8 pb = __builtin_bit_cast(bf16x8, pu);
            Od0  = __builtin_amdgcn_mfma_f32_32x32x16_bf16(va0,  pb, Od0,  0, 0, 0);
            Od1  = __builtin_amdgcn_mfma_f32_32x32x16_bf16(va1,  pb, Od1,  0, 0, 0);
            Lacc = __builtin_amdgcn_mfma_f32_32x32x16_bf16(ones, pb, Lacc, 0, 0, 0);
        }
        __builtin_amdgcn_s_setprio(0);

        __syncthreads();
        cur ^= 1;
    }

    const int bb = bh >> 4;
    const int hh = bh & 15;
    const float inv = 1.0f / Lacc[0];
    float* op = out + (size_t)qrow * (BATCH * DMODEL) + bb * DMODEL + hh * HDIM;
#pragma unroll
    for (int gg = 0; gg < 4; ++gg) {
        const int d0 = gg * 8 + half * 4;
        float4 v0, v1;
        v0.x = Od0[gg * 4 + 0] * inv; v0.y = Od0[gg * 4 + 1] * inv;
        v0.z = Od0[gg * 4 + 2] * inv; v0.w = Od0[gg * 4 + 3] * inv;
        v1.x = Od1[gg * 4 + 0] * inv; v1.y = Od1[gg * 4 + 1] * inv;
        v1.z = Od1[gg * 4 + 2] * inv; v1.w = Od1[gg * 4 + 3] * inv;
        *(float4*)(op + d0)      = v0;
        *(float4*)(op + 32 + d0) = v1;
    }
}

extern "C" void kernel_launch(void* const* d_in, const int* in_sizes, int n_in,
                              void* d_out, int out_size, void* d_ws, size_t ws_size,
                              hipStream_t stream) {
    const float* q  = (const float*)d_in[0];
    const float* k  = (const float*)d_in[1];
    const float* v  = (const float*)d_in[2];
    const float* Wq = (const float*)d_in[3];
    const float* bq = (const float*)d_in[4];
    const float* Wk = (const float*)d_in[5];
    const float* bk = (const float*)d_in[6];
    const float* Wv = (const float*)d_in[7];
    const float* bv = (const float*)d_in[8];
    unsigned short* ws = (unsigned short*)d_ws;
    float* out = (float*)d_out;

    proj_kernel<<<dim3(768), dim3(256), 0, stream>>>(q, k, v, Wq, Wk, Wv, bq, bk, bv, ws);
    attn_kernel<<<dim3(256), dim3(512), 0, stream>>>(ws, out);
}

// Round 10
// 148.278 us; speedup vs baseline: 1.1601x; 1.0191x over previous
//
#include <hip/hip_runtime.h>
#include <hip/hip_bf16.h>

#define S_LEN 2048
#define BATCH 2
#define DMODEL 1024
#define NHEAD 16
#define HDIM 64
#define MTOT (S_LEN * BATCH)
#define QKV_ELEMS ((size_t)MTOT * DMODEL)

typedef __bf16 bf16x8 __attribute__((ext_vector_type(8)));
typedef unsigned short u16x8 __attribute__((ext_vector_type(8)));
typedef float f32x4 __attribute__((ext_vector_type(4)));
typedef float f32x16 __attribute__((ext_vector_type(16)));
typedef unsigned int u32x4 __attribute__((ext_vector_type(4)));

__device__ __forceinline__ unsigned short f2bf(float f) {
    unsigned int u = __float_as_uint(f);
    u += 0x7FFFu + ((u >> 16) & 1u);
    return (unsigned short)(u >> 16);
}

// compiler-emitted v_cvt_pk_bf16_f32 (m240: do NOT hand-asm this).
__device__ __forceinline__ unsigned int pack2(float lo, float hi) {
    __hip_bfloat162 h = __float22bfloat162_rn(make_float2(lo, hi));
    unsigned int r;
    __builtin_memcpy(&r, &h, 4);
    return r;
}

__device__ __forceinline__ void gload_lds16(const void* g, void* l) {
    __builtin_amdgcn_global_load_lds(
        (const __attribute__((address_space(1))) unsigned int*)g,
        (__attribute__((address_space(3))) unsigned int*)l, 16, 0, 0);
}

// ---------------------------------------------------------------------------
// Projection GEMM (frozen from R6 — chunked XCD swizzle verified 114->53 us).
// Q: [b][h][s][d] scaled by 0.125*log2(e).  K: [b][h][s][d].  V: [b][h][d][s].
// ---------------------------------------------------------------------------
#define PBM 128
#define PBN 128
#define PBK 32
#define PLDS 48
#define QSCALE 0.18033688011112042f   // 0.125 * log2(e)

__global__ __launch_bounds__(256) void proj_kernel(
        const float* __restrict__ Xq, const float* __restrict__ Xk,
        const float* __restrict__ Xv, const float* __restrict__ Wq,
        const float* __restrict__ Wk, const float* __restrict__ Wv,
        const float* __restrict__ bq, const float* __restrict__ bk,
        const float* __restrict__ bv, unsigned short* __restrict__ ws)
{
    const int work = (blockIdx.x & 7) * 96 + (blockIdx.x >> 3);   // 0..767
    const int t    = work >> 8;
    const int rem  = work & 255;
    const int m0   = (rem >> 3) * PBM;
    const int n0   = (rem & 7) * PBN;

    const float* X    = (t == 0) ? Xq : (t == 1) ? Xk : Xv;
    const float* W    = (t == 0) ? Wq : (t == 1) ? Wk : Wv;
    const float* bias = (t == 0) ? bq : (t == 1) ? bk : bv;
    unsigned short* out = ws + (size_t)t * QKV_ELEMS;
    const float scale = (t == 0) ? QSCALE : 1.0f;

    __shared__ __align__(16) unsigned short lds[(PBM + PBN) * PLDS];
    unsigned short* Alds = lds;
    unsigned short* Blds = lds + PBM * PLDS;

    const int tid = threadIdx.x;
    const int wave = tid >> 6;
    const int lane = tid & 63;
    const int lrow = lane & 15;
    const int lg   = lane >> 4;
    const int wr = (wave >> 1) * 64;
    const int wc = (wave & 1) * 64;

    f32x4 acc[4][4];
#pragma unroll
    for (int i = 0; i < 4; ++i)
#pragma unroll
        for (int j = 0; j < 4; ++j)
            acc[i][j] = (f32x4){0.f, 0.f, 0.f, 0.f};

    const int sr = tid >> 3;
    const int sg = tid & 7;

    for (int k0 = 0; k0 < DMODEL; k0 += PBK) {
        __syncthreads();
#pragma unroll
        for (int it = 0; it < 4; ++it) {
            const int row = sr + it * 32;
            const float4 va = *(const float4*)(X + (size_t)(m0 + row) * DMODEL + k0 + sg * 4);
            const float4 vb = *(const float4*)(W + (size_t)(n0 + row) * DMODEL + k0 + sg * 4);
            ushort4 ha, hb;
            ha.x = f2bf(va.x); ha.y = f2bf(va.y); ha.z = f2bf(va.z); ha.w = f2bf(va.w);
            hb.x = f2bf(vb.x); hb.y = f2bf(vb.y); hb.z = f2bf(vb.z); hb.w = f2bf(vb.w);
            *(ushort4*)&Alds[row * PLDS + sg * 4] = ha;
            *(ushort4*)&Blds[row * PLDS + sg * 4] = hb;
        }
        __syncthreads();

        bf16x8 af[4], bw[4];
#pragma unroll
        for (int i = 0; i < 4; ++i) {
            af[i] = *(const bf16x8*)&Alds[(wr + i * 16 + lrow) * PLDS + lg * 8];
            bw[i] = *(const bf16x8*)&Blds[(wc + i * 16 + lrow) * PLDS + lg * 8];
        }
#pragma unroll
        for (int i = 0; i < 4; ++i)
#pragma unroll
            for (int j = 0; j < 4; ++j)
                acc[i][j] = __builtin_amdgcn_mfma_f32_16x16x32_bf16(af[i], bw[j], acc[i][j], 0, 0, 0);
    }

#pragma unroll
    for (int j = 0; j < 4; ++j) {
        const int n  = n0 + wc + j * 16 + lrow;
        const float bv_ = bias[n];
        const int h  = n >> 6;
        const int dd = n & 63;
#pragma unroll
        for (int i = 0; i < 4; ++i) {
#pragma unroll
            for (int r = 0; r < 4; ++r) {
                const int m = m0 + wr + i * 16 + lg * 4 + r;
                const int s = m >> 1;
                const int b = m & 1;
                const float v = (acc[i][j][r] + bv_) * scale;
                size_t idx;
                if (t == 2)
                    idx = ((size_t)((b * NHEAD + h) * HDIM + dd)) * S_LEN + s;
                else
                    idx = ((size_t)((b * NHEAD + h) * S_LEN + s)) * HDIM + dd;
                out[idx] = f2bf(v);
            }
        }
    }
}

// ---------------------------------------------------------------------------
// Flash attention: swapped-QK^T 32x32, per-tile path identical to R9.
// Grid A/B: 512 blocks x 256 threads (4 waves, 128 q) -> 48 KB LDS/block ->
// 2-3 blocks/CU co-resident (occupancy lever; R9 was 1 block/CU).
// ---------------------------------------------------------------------------
#define NT (S_LEN / 64)

__global__ __launch_bounds__(256) void attn_kernel(
        const unsigned short* __restrict__ ws, float* __restrict__ out)
{
    const unsigned short* Qw = ws;
    const unsigned short* Kw = ws + QKV_ELEMS;
    const unsigned short* Vw = ws + 2 * QKV_ELEMS;   // [b][h][d][s]

    // 512 blocks: 4 bh per XCD, 16 q-chunks of 128 per bh
    const int bid = blockIdx.x;
    const int idx = bid >> 3;                        // 0..63
    const int bh  = (bid & 7) * 4 + (idx >> 4);      // 0..31
    const int q0  = (idx & 15) * 128;

    __shared__ __align__(16) unsigned short Kbuf[2][64 * 64];
    __shared__ __align__(16) unsigned short Vbuf[2][64 * 64];
    __shared__ unsigned int Pu[4][32 * 32];          // per-wave [keypair][q]

    const int tid  = threadIdx.x;
    const int wave = tid >> 6;
    const int lane = tid & 63;
    const int l31  = lane & 31;
    const int half = lane >> 5;

    const size_t base = (size_t)bh * S_LEN * HDIM;
    const int qrow = q0 + wave * 32 + l31;

    bf16x8 qf[4];
#pragma unroll
    for (int c = 0; c < 4; ++c)
        qf[c] = *(const bf16x8*)(Qw + base + (size_t)qrow * HDIM + c * 16 + half * 8);

    // all-ones bf16 A-fragment for row-sum MFMA (layout-invariant)
    bf16x8 ones;
    {
        u16x8 o;
#pragma unroll
        for (int e = 0; e < 8; ++e) o[e] = 0x3F80;
        ones = __builtin_bit_cast(bf16x8, o);
    }

    f32x16 Od0, Od1, Lacc;
#pragma unroll
    for (int i = 0; i < 16; ++i) { Od0[i] = 0.f; Od1[i] = 0.f; Lacc[i] = 0.f; }
    float mrun = -__builtin_inff();

    int g_[4];
#pragma unroll
    for (int c = 0; c < 4; ++c) g_[c] = ((c * 2 + half) ^ (l31 & 7)) * 8;

    // staging: 256 threads, 2 x 16B per tensor per tile (rows r0, r0+8)
    const int strow = lane >> 3;                     // 0..7
    const int sgrp  = (lane & 7) ^ strow;            // XOR swizzle (row&7 same for r0,r0+8)
    const int r0    = wave * 16 + strow;
    const int dsto  = wave * 1024 + lane * 8;        // ushort elems; +512 for row+8

    gload_lds16(Kw + base + (size_t)r0 * HDIM + sgrp * 8,        &Kbuf[0][dsto]);
    gload_lds16(Kw + base + (size_t)(r0 + 8) * HDIM + sgrp * 8,  &Kbuf[0][dsto + 512]);
    gload_lds16(Vw + base + (size_t)r0 * S_LEN + sgrp * 8,       &Vbuf[0][dsto]);
    gload_lds16(Vw + base + (size_t)(r0 + 8) * S_LEN + sgrp * 8, &Vbuf[0][dsto + 512]);
    __syncthreads();

    int cur = 0;
    for (int t = 0; t < NT; ++t) {
        if (t + 1 < NT) {
            const int sn = (t + 1) * 64;
            gload_lds16(Kw + base + (size_t)(sn + r0) * HDIM + sgrp * 8,      &Kbuf[cur ^ 1][dsto]);
            gload_lds16(Kw + base + (size_t)(sn + r0 + 8) * HDIM + sgrp * 8,  &Kbuf[cur ^ 1][dsto + 512]);
            gload_lds16(Vw + base + (size_t)r0 * S_LEN + sn + sgrp * 8,       &Vbuf[cur ^ 1][dsto]);
            gload_lds16(Vw + base + (size_t)(r0 + 8) * S_LEN + sn + sgrp * 8, &Vbuf[cur ^ 1][dsto + 512]);
        }

        const unsigned short* Klds = Kbuf[cur];
        const unsigned short* Vlds = Vbuf[cur];

        f32x16 S0, S1;
#pragma unroll
        for (int i = 0; i < 16; ++i) { S0[i] = 0.f; S1[i] = 0.f; }
        __builtin_amdgcn_s_setprio(1);
#pragma unroll
        for (int c = 0; c < 4; ++c) {
            const bf16x8 ka0 = *(const bf16x8*)&Klds[l31 * 64 + g_[c]];
            const bf16x8 ka1 = *(const bf16x8*)&Klds[(32 + l31) * 64 + g_[c]];
            S0 = __builtin_amdgcn_mfma_f32_32x32x16_bf16(ka0, qf[c], S0, 0, 0, 0);
            S1 = __builtin_amdgcn_mfma_f32_32x32x16_bf16(ka1, qf[c], S1, 0, 0, 0);
        }
        __builtin_amdgcn_s_setprio(0);

        // ---- max (max3-friendly triplet tree) ----
        float m16[16];
#pragma unroll
        for (int i = 0; i < 16; ++i) m16[i] = fmaxf(S0[i], S1[i]);
        float a0 = fmaxf(fmaxf(m16[0],  m16[1]),  m16[2]);
        float a1 = fmaxf(fmaxf(m16[3],  m16[4]),  m16[5]);
        float a2 = fmaxf(fmaxf(m16[6],  m16[7]),  m16[8]);
        float a3 = fmaxf(fmaxf(m16[9],  m16[10]), m16[11]);
        float a4 = fmaxf(fmaxf(m16[12], m16[13]), m16[14]);
        float b0 = fmaxf(fmaxf(a0, a1), a2);
        float b1 = fmaxf(fmaxf(a3, a4), m16[15]);
        float mx = fmaxf(b0, b1);
        mx = fmaxf(mx, __shfl_xor(mx, 32, 64));

        if (!__all(mx - mrun <= 8.0f)) {         // defer-max THR=8
            const float mnew = fmaxf(mrun, mx);
            const float ex   = exp2f(mrun - mnew);
            mrun = mnew;
            Od0 *= ex;
            Od1 *= ex;
            Lacc *= ex;
        }

#pragma unroll
        for (int i = 0; i < 16; ++i) S0[i] = exp2f(S0[i] - mrun);
#pragma unroll
        for (int i = 0; i < 16; ++i) S1[i] = exp2f(S1[i] - mrun);

        // ---- P^T -> per-wave LDS as packed key-pairs ----
#pragma unroll
        for (int w = 0; w < 8; ++w) {
            const unsigned int pk0 = pack2(S0[2 * w], S0[2 * w + 1]);
            const unsigned int pk1 = pack2(S1[2 * w], S1[2 * w + 1]);
            const int kp = (w & 1) + 4 * (w >> 1) + 2 * half;
            Pu[wave][kp * 32 + l31]        = pk0;
            Pu[wave][(16 + kp) * 32 + l31] = pk1;
        }
        __asm__ volatile("" ::: "memory");

        // ---- PV + ones-row-sum: O^T += V^T.P^T ; Lacc += 1.P^T ----
        __builtin_amdgcn_s_setprio(1);
#pragma unroll
        for (int c = 0; c < 4; ++c) {
            const bf16x8 va0 = *(const bf16x8*)&Vlds[l31 * 64 + g_[c]];
            const bf16x8 va1 = *(const bf16x8*)&Vlds[(32 + l31) * 64 + g_[c]];
            u32x4 pu;
#pragma unroll
            for (int e = 0; e < 4; ++e)
                pu[e] = Pu[wave][(c * 8 + half * 4 + e) * 32 + l31];
            const bf16x8 pb = __builtin_bit_cast(bf16x8, pu);
            Od0  = __builtin_amdgcn_mfma_f32_32x32x16_bf16(va0,  pb, Od0,  0, 0, 0);
            Od1  = __builtin_amdgcn_mfma_f32_32x32x16_bf16(va1,  pb, Od1,  0, 0, 0);
            Lacc = __builtin_amdgcn_mfma_f32_32x32x16_bf16(ones, pb, Lacc, 0, 0, 0);
        }
        __builtin_amdgcn_s_setprio(0);

        __syncthreads();
        cur ^= 1;
    }

    const int bb = bh >> 4;
    const int hh = bh & 15;
    const float inv = 1.0f / Lacc[0];
    float* op = out + (size_t)qrow * (BATCH * DMODEL) + bb * DMODEL + hh * HDIM;
#pragma unroll
    for (int gg = 0; gg < 4; ++gg) {
        const int d0 = gg * 8 + half * 4;
        float4 v0, v1;
        v0.x = Od0[gg * 4 + 0] * inv; v0.y = Od0[gg * 4 + 1] * inv;
        v0.z = Od0[gg * 4 + 2] * inv; v0.w = Od0[gg * 4 + 3] * inv;
        v1.x = Od1[gg * 4 + 0] * inv; v1.y = Od1[gg * 4 + 1] * inv;
        v1.z = Od1[gg * 4 + 2] * inv; v1.w = Od1[gg * 4 + 3] * inv;
        *(float4*)(op + d0)      = v0;
        *(float4*)(op + 32 + d0) = v1;
    }
}

extern "C" void kernel_launch(void* const* d_in, const int* in_sizes, int n_in,
                              void* d_out, int out_size, void* d_ws, size_t ws_size,
                              hipStream_t stream) {
    const float* q  = (const float*)d_in[0];
    const float* k  = (const float*)d_in[1];
    const float* v  = (const float*)d_in[2];
    const float* Wq = (const float*)d_in[3];
    const float* bq = (const float*)d_in[4];
    const float* Wk = (const float*)d_in[5];
    const float* bk = (const float*)d_in[6];
    const float* Wv = (const float*)d_in[7];
    const float* bv = (const float*)d_in[8];
    unsigned short* ws = (unsigned short*)d_ws;
    float* out = (float*)d_out;

    proj_kernel<<<dim3(768), dim3(256), 0, stream>>>(q, k, v, Wq, Wk, Wv, bq, bk, bv, ws);
    attn_kernel<<<dim3(512), dim3(256), 0, stream>>>(ws, out);
}

// Round 11
// 143.428 us; speedup vs baseline: 1.1994x; 1.0338x over previous
//
#include <hip/hip_runtime.h>
#include <hip/hip_bf16.h>

#define S_LEN 2048
#define BATCH 2
#define DMODEL 1024
#define NHEAD 16
#define HDIM 64
#define MTOT (S_LEN * BATCH)
#define QKV_ELEMS ((size_t)MTOT * DMODEL)

typedef __bf16 bf16x8 __attribute__((ext_vector_type(8)));
typedef unsigned short u16x8 __attribute__((ext_vector_type(8)));
typedef float f32x4 __attribute__((ext_vector_type(4)));
typedef unsigned int u32x4 __attribute__((ext_vector_type(4)));

__device__ __forceinline__ unsigned short f2bf(float f) {
    unsigned int u = __float_as_uint(f);
    u += 0x7FFFu + ((u >> 16) & 1u);
    return (unsigned short)(u >> 16);
}

// compiler-emitted v_cvt_pk_bf16_f32 (m240: do NOT hand-asm this).
__device__ __forceinline__ unsigned int pack2(float lo, float hi) {
    __hip_bfloat162 h = __float22bfloat162_rn(make_float2(lo, hi));
    unsigned int r;
    __builtin_memcpy(&r, &h, 4);
    return r;
}

__device__ __forceinline__ void gload_lds16(const void* g, void* l) {
    __builtin_amdgcn_global_load_lds(
        (const __attribute__((address_space(1))) unsigned int*)g,
        (__attribute__((address_space(3))) unsigned int*)l, 16, 0, 0);
}

// ---------------------------------------------------------------------------
// Projection GEMM (frozen from R6 — chunked XCD swizzle verified 114->53 us).
// Q: [b][h][s][d] scaled by 0.125*log2(e).  K: [b][h][s][d].  V: [b][h][d][s].
// ---------------------------------------------------------------------------
#define PBM 128
#define PBN 128
#define PBK 32
#define PLDS 48
#define QSCALE 0.18033688011112042f   // 0.125 * log2(e)

__global__ __launch_bounds__(256) void proj_kernel(
        const float* __restrict__ Xq, const float* __restrict__ Xk,
        const float* __restrict__ Xv, const float* __restrict__ Wq,
        const float* __restrict__ Wk, const float* __restrict__ Wv,
        const float* __restrict__ bq, const float* __restrict__ bk,
        const float* __restrict__ bv, unsigned short* __restrict__ ws)
{
    const int work = (blockIdx.x & 7) * 96 + (blockIdx.x >> 3);   // 0..767
    const int t    = work >> 8;
    const int rem  = work & 255;
    const int m0   = (rem >> 3) * PBM;
    const int n0   = (rem & 7) * PBN;

    const float* X    = (t == 0) ? Xq : (t == 1) ? Xk : Xv;
    const float* W    = (t == 0) ? Wq : (t == 1) ? Wk : Wv;
    const float* bias = (t == 0) ? bq : (t == 1) ? bk : bv;
    unsigned short* out = ws + (size_t)t * QKV_ELEMS;
    const float scale = (t == 0) ? QSCALE : 1.0f;

    __shared__ __align__(16) unsigned short lds[(PBM + PBN) * PLDS];
    unsigned short* Alds = lds;
    unsigned short* Blds = lds + PBM * PLDS;

    const int tid = threadIdx.x;
    const int wave = tid >> 6;
    const int lane = tid & 63;
    const int lrow = lane & 15;
    const int lg   = lane >> 4;
    const int wr = (wave >> 1) * 64;
    const int wc = (wave & 1) * 64;

    f32x4 acc[4][4];
#pragma unroll
    for (int i = 0; i < 4; ++i)
#pragma unroll
        for (int j = 0; j < 4; ++j)
            acc[i][j] = (f32x4){0.f, 0.f, 0.f, 0.f};

    const int sr = tid >> 3;
    const int sg = tid & 7;

    for (int k0 = 0; k0 < DMODEL; k0 += PBK) {
        __syncthreads();
#pragma unroll
        for (int it = 0; it < 4; ++it) {
            const int row = sr + it * 32;
            const float4 va = *(const float4*)(X + (size_t)(m0 + row) * DMODEL + k0 + sg * 4);
            const float4 vb = *(const float4*)(W + (size_t)(n0 + row) * DMODEL + k0 + sg * 4);
            ushort4 ha, hb;
            ha.x = f2bf(va.x); ha.y = f2bf(va.y); ha.z = f2bf(va.z); ha.w = f2bf(va.w);
            hb.x = f2bf(vb.x); hb.y = f2bf(vb.y); hb.z = f2bf(vb.z); hb.w = f2bf(vb.w);
            *(ushort4*)&Alds[row * PLDS + sg * 4] = ha;
            *(ushort4*)&Blds[row * PLDS + sg * 4] = hb;
        }
        __syncthreads();

        bf16x8 af[4], bw[4];
#pragma unroll
        for (int i = 0; i < 4; ++i) {
            af[i] = *(const bf16x8*)&Alds[(wr + i * 16 + lrow) * PLDS + lg * 8];
            bw[i] = *(const bf16x8*)&Blds[(wc + i * 16 + lrow) * PLDS + lg * 8];
        }
#pragma unroll
        for (int i = 0; i < 4; ++i)
#pragma unroll
            for (int j = 0; j < 4; ++j)
                acc[i][j] = __builtin_amdgcn_mfma_f32_16x16x32_bf16(af[i], bw[j], acc[i][j], 0, 0, 0);
    }

#pragma unroll
    for (int j = 0; j < 4; ++j) {
        const int n  = n0 + wc + j * 16 + lrow;
        const float bv_ = bias[n];
        const int h  = n >> 6;
        const int dd = n & 63;
#pragma unroll
        for (int i = 0; i < 4; ++i) {
#pragma unroll
            for (int r = 0; r < 4; ++r) {
                const int m = m0 + wr + i * 16 + lg * 4 + r;
                const int s = m >> 1;
                const int b = m & 1;
                const float v = (acc[i][j][r] + bv_) * scale;
                size_t idx;
                if (t == 2)
                    idx = ((size_t)((b * NHEAD + h) * HDIM + dd)) * S_LEN + s;
                else
                    idx = ((size_t)((b * NHEAD + h) * S_LEN + s)) * HDIM + dd;
                out[idx] = f2bf(v);
            }
        }
    }
}

// ---------------------------------------------------------------------------
// Flash attention, 16-q-per-wave 16x16x32 variant (occupancy lever):
//   8 waves x 16 q = 128 q/block, 512 blocks x 512 thr -> 4096 waves total
//   = 16 waves/CU (50% cap, 2 blocks/CU co-resident).
//   S^T = K.Q^T per 16-key tile (4 tiles/64-key block); C/D layout per
//   m89/m91 (col=lane&15, row=(lane>>4)*4+r).  A/B share assumed k map
//   (layout-invariant).  P via per-wave LDS (stride-17 rows, conflict-free),
//   read with the SAME slot->key map as V.  Lacc = ones-MFMA row sum.
//   dbuf K/V gload_lds staging, defer-max THR=8, setprio on MFMA clusters.
// ---------------------------------------------------------------------------
#define NT (S_LEN / 64)
#define PUSTR 17   // Pu row stride (u32): conflict-free reads (4lg+lrow <= 2-way)

__global__ __launch_bounds__(512, 4) void attn_kernel(
        const unsigned short* __restrict__ ws, float* __restrict__ out)
{
    const unsigned short* Qw = ws;
    const unsigned short* Kw = ws + QKV_ELEMS;
    const unsigned short* Vw = ws + 2 * QKV_ELEMS;   // [b][h][d][s]

    // 512 blocks: 4 bh per XCD, 16 q-chunks of 128 per bh
    const int bid = blockIdx.x;
    const int idx = bid >> 3;                        // 0..63
    const int bh  = (bid & 7) * 4 + (idx >> 4);      // 0..31
    const int q0  = (idx & 15) * 128;

    __shared__ __align__(16) unsigned short Kbuf[2][64 * 64];
    __shared__ __align__(16) unsigned short Vbuf[2][64 * 64];
    __shared__ unsigned int Pu[8][32 * PUSTR];       // per-wave [keypair][q]

    const int tid  = threadIdx.x;
    const int wave = tid >> 6;
    const int lane = tid & 63;
    const int lrow = lane & 15;
    const int lg   = lane >> 4;

    const size_t base = (size_t)bh * S_LEN * HDIM;
    const int qrow = q0 + wave * 16 + lrow;

    // Q^T B-frags: lane covers q = lrow (col), d = c*32 + lg*8 + j
    bf16x8 qf[2];
#pragma unroll
    for (int c = 0; c < 2; ++c)
        qf[c] = *(const bf16x8*)(Qw + base + (size_t)qrow * HDIM + c * 32 + lg * 8);

    // all-ones bf16 A-fragment for row-sum MFMA (layout-invariant)
    bf16x8 ones;
    {
        u16x8 o;
#pragma unroll
        for (int e = 0; e < 8; ++e) o[e] = 0x3F80;
        ones = __builtin_bit_cast(bf16x8, o);
    }

    f32x4 O[4], Lacc;
#pragma unroll
    for (int dt = 0; dt < 4; ++dt) O[dt] = (f32x4){0.f, 0.f, 0.f, 0.f};
    Lacc = (f32x4){0.f, 0.f, 0.f, 0.f};
    float mrun = -__builtin_inff();

    // staging: 512 threads, one 16B gload per tensor per tile
    const int srow = tid >> 3;                 // 0..63
    const int sgrp = (tid & 7) ^ (srow & 7);   // XOR-swizzled source group
    const int dsto = tid * 8;

    gload_lds16(Kw + base + (size_t)srow * HDIM + sgrp * 8,  &Kbuf[0][dsto]);
    gload_lds16(Vw + base + (size_t)srow * S_LEN + sgrp * 8, &Vbuf[0][dsto]);
    __syncthreads();

    int cur = 0;
    for (int t = 0; t < NT; ++t) {
        if (t + 1 < NT) {
            const int sn = (t + 1) * 64;
            gload_lds16(Kw + base + (size_t)(sn + srow) * HDIM + sgrp * 8, &Kbuf[cur ^ 1][dsto]);
            gload_lds16(Vw + base + (size_t)srow * S_LEN + sn + sgrp * 8, &Vbuf[cur ^ 1][dsto]);
        }

        const unsigned short* Klds = Kbuf[cur];
        const unsigned short* Vlds = Vbuf[cur];

        // ---- QK: S[kt] = K(16 keys) . Q^T, kt = 0..3, k(=d) = 64 via c=0,1 ----
        f32x4 S[4];
#pragma unroll
        for (int kt = 0; kt < 4; ++kt) S[kt] = (f32x4){0.f, 0.f, 0.f, 0.f};
        __builtin_amdgcn_s_setprio(1);
#pragma unroll
        for (int kt = 0; kt < 4; ++kt) {
#pragma unroll
            for (int c = 0; c < 2; ++c) {
                const int g = ((c * 4 + lg) ^ (lrow & 7)) * 8;
                const bf16x8 ka = *(const bf16x8*)&Klds[(kt * 16 + lrow) * 64 + g];
                S[kt] = __builtin_amdgcn_mfma_f32_16x16x32_bf16(ka, qf[c], S[kt], 0, 0, 0);
            }
        }
        __builtin_amdgcn_s_setprio(0);

        // ---- max over 16 regs + 2 shuffles (q column spans lg groups) ----
        float m0_ = fmaxf(fmaxf(S[0][0], S[0][1]), fmaxf(S[0][2], S[0][3]));
        float m1_ = fmaxf(fmaxf(S[1][0], S[1][1]), fmaxf(S[1][2], S[1][3]));
        float m2_ = fmaxf(fmaxf(S[2][0], S[2][1]), fmaxf(S[2][2], S[2][3]));
        float m3_ = fmaxf(fmaxf(S[3][0], S[3][1]), fmaxf(S[3][2], S[3][3]));
        float mx = fmaxf(fmaxf(m0_, m1_), fmaxf(m2_, m3_));
        mx = fmaxf(mx, __shfl_xor(mx, 16, 64));
        mx = fmaxf(mx, __shfl_xor(mx, 32, 64));

        if (!__all(mx - mrun <= 8.0f)) {         // defer-max THR=8
            const float mnew = fmaxf(mrun, mx);
            const float ex   = exp2f(mrun - mnew);
            mrun = mnew;
#pragma unroll
            for (int dt = 0; dt < 4; ++dt) O[dt] *= ex;
            Lacc *= ex;
        }

#pragma unroll
        for (int kt = 0; kt < 4; ++kt)
#pragma unroll
            for (int r = 0; r < 4; ++r)
                S[kt][r] = exp2f(S[kt][r] - mrun);

        // ---- P^T -> Pu (C/D layout: key = kt*16 + lg*4 + r; adjacent pairs) ----
#pragma unroll
        for (int kt = 0; kt < 4; ++kt) {
#pragma unroll
            for (int i = 0; i < 2; ++i) {
                const unsigned int dw = pack2(S[kt][2 * i], S[kt][2 * i + 1]);
                const int kp = kt * 8 + lg * 2 + i;
                Pu[wave][kp * PUSTR + lrow] = dw;
            }
        }
        __asm__ volatile("" ::: "memory");

        // ---- PV: O^T[d][q] += V^T.P^T ; Lacc += ones.P^T ----
        __builtin_amdgcn_s_setprio(1);
        bf16x8 pb[2];
#pragma unroll
        for (int c = 0; c < 2; ++c) {
            u32x4 pu;
#pragma unroll
            for (int e = 0; e < 4; ++e)
                pu[e] = Pu[wave][(c * 16 + lg * 4 + e) * PUSTR + lrow];
            pb[c] = __builtin_bit_cast(bf16x8, pu);
        }
#pragma unroll
        for (int dt = 0; dt < 4; ++dt) {
#pragma unroll
            for (int c = 0; c < 2; ++c) {
                const int g = ((c * 4 + lg) ^ (lrow & 7)) * 8;
                const bf16x8 va = *(const bf16x8*)&Vlds[(dt * 16 + lrow) * 64 + g];
                O[dt] = __builtin_amdgcn_mfma_f32_16x16x32_bf16(va, pb[c], O[dt], 0, 0, 0);
            }
        }
        Lacc = __builtin_amdgcn_mfma_f32_16x16x32_bf16(ones, pb[0], Lacc, 0, 0, 0);
        Lacc = __builtin_amdgcn_mfma_f32_16x16x32_bf16(ones, pb[1], Lacc, 0, 0, 0);
        __builtin_amdgcn_s_setprio(0);

        __syncthreads();
        cur ^= 1;
    }

    // epilogue: normalize, write fp32 out[s][b][h*64+d]; d = dt*16 + lg*4 + r
    const int bb = bh >> 4;
    const int hh = bh & 15;
    const float inv = 1.0f / Lacc[0];
    float* op = out + (size_t)qrow * (BATCH * DMODEL) + bb * DMODEL + hh * HDIM;
#pragma unroll
    for (int dt = 0; dt < 4; ++dt) {
        float4 v;
        v.x = O[dt][0] * inv; v.y = O[dt][1] * inv;
        v.z = O[dt][2] * inv; v.w = O[dt][3] * inv;
        *(float4*)(op + dt * 16 + lg * 4) = v;
    }
}

extern "C" void kernel_launch(void* const* d_in, const int* in_sizes, int n_in,
                              void* d_out, int out_size, void* d_ws, size_t ws_size,
                              hipStream_t stream) {
    const float* q  = (const float*)d_in[0];
    const float* k  = (const float*)d_in[1];
    const float* v  = (const float*)d_in[2];
    const float* Wq = (const float*)d_in[3];
    const float* bq = (const float*)d_in[4];
    const float* Wk = (const float*)d_in[5];
    const float* bk = (const float*)d_in[6];
    const float* Wv = (const float*)d_in[7];
    const float* bv = (const float*)d_in[8];
    unsigned short* ws = (unsigned short*)d_ws;
    float* out = (float*)d_out;

    proj_kernel<<<dim3(768), dim3(256), 0, stream>>>(q, k, v, Wq, Wk, Wv, bq, bk, bv, ws);
    attn_kernel<<<dim3(512), dim3(512), 0, stream>>>(ws, out);
}

// Round 12
// 138.063 us; speedup vs baseline: 1.2460x; 1.0389x over previous
//
#include <hip/hip_runtime.h>
#include <hip/hip_bf16.h>

#define S_LEN 2048
#define BATCH 2
#define DMODEL 1024
#define NHEAD 16
#define HDIM 64
#define MTOT (S_LEN * BATCH)
#define QKV_ELEMS ((size_t)MTOT * DMODEL)          // 4194304
#define XOFF (3 * QKV_ELEMS)                       // bf16 X' segment base (ushorts)
#define WOFF (XOFF + 3 * QKV_ELEMS)                // bf16 W' segment base
#define WSEG ((size_t)DMODEL * DMODEL)             // 1048576

typedef __bf16 bf16x8 __attribute__((ext_vector_type(8)));
typedef unsigned short u16x8 __attribute__((ext_vector_type(8)));
typedef float f32x4 __attribute__((ext_vector_type(4)));
typedef unsigned int u32x4 __attribute__((ext_vector_type(4)));

__device__ __forceinline__ unsigned short f2bf(float f) {
    unsigned int u = __float_as_uint(f);
    u += 0x7FFFu + ((u >> 16) & 1u);
    return (unsigned short)(u >> 16);
}

// compiler-emitted v_cvt_pk_bf16_f32 (m240: do NOT hand-asm this).
__device__ __forceinline__ unsigned int pack2(float lo, float hi) {
    __hip_bfloat162 h = __float22bfloat162_rn(make_float2(lo, hi));
    unsigned int r;
    __builtin_memcpy(&r, &h, 4);
    return r;
}

__device__ __forceinline__ void gload_lds16(const void* g, void* l) {
    __builtin_amdgcn_global_load_lds(
        (const __attribute__((address_space(1))) unsigned int*)g,
        (__attribute__((address_space(3))) unsigned int*)l, 16, 0, 0);
}

// ---------------------------------------------------------------------------
// cvt_kernel: fp32 -> bf16 for X (3x 4M elems) and W (3x 1M elems) into ws.
// Layouts unchanged (row-major [*][k]); pure streaming, float4 + cvt_pk.
// ---------------------------------------------------------------------------
__global__ __launch_bounds__(256) void cvt_kernel(
        const float* __restrict__ Xq, const float* __restrict__ Xk,
        const float* __restrict__ Xv, const float* __restrict__ Wq,
        const float* __restrict__ Wk, const float* __restrict__ Wv,
        unsigned short* __restrict__ ws)
{
    const int seg = blockIdx.y;
    const float* src;
    unsigned short* dst;
    int n4;
    if (seg < 3) {
        src = (seg == 0) ? Xq : (seg == 1) ? Xk : Xv;
        dst = ws + XOFF + (size_t)seg * QKV_ELEMS;
        n4  = (int)(QKV_ELEMS / 4);
    } else {
        const int s = seg - 3;
        src = (s == 0) ? Wq : (s == 1) ? Wk : Wv;
        dst = ws + WOFF + (size_t)s * WSEG;
        n4  = (int)(WSEG / 4);
    }
    const int stride = gridDim.x * blockDim.x;
    for (int i = blockIdx.x * blockDim.x + threadIdx.x; i < n4; i += stride) {
        const float4 v = ((const float4*)src)[i];
        uint2 o;
        o.x = pack2(v.x, v.y);
        o.y = pack2(v.z, v.w);
        ((uint2*)dst)[i] = o;
    }
}

// ---------------------------------------------------------------------------
// Projection GEMM on pre-converted bf16 (m97 structure): gload_lds 16B
// staging (zero staging VALU), double-buffered LDS, ONE barrier per K-step.
// Chunk-XOR swizzle on 16B groups (read pattern = 8 accesses/bank, optimal).
// Chunked XCD swizzle grid (96 blocks/XCD).  Epilogue identical to verified.
// Q: [b][h][s][d] scaled by 0.125*log2(e).  K: [b][h][s][d].  V: [b][h][d][s].
// ---------------------------------------------------------------------------
#define PBM 128
#define PBN 128
#define PBK 32
#define QSCALE 0.18033688011112042f   // 0.125 * log2(e)

__global__ __launch_bounds__(256, 3) void proj_kernel(
        const unsigned short* __restrict__ wsin,
        const float* __restrict__ bq, const float* __restrict__ bk,
        const float* __restrict__ bv, unsigned short* __restrict__ wsout)
{
    const int work = (blockIdx.x & 7) * 96 + (blockIdx.x >> 3);   // 0..767
    const int t    = work >> 8;
    const int rem  = work & 255;
    const int m0   = (rem >> 3) * PBM;
    const int n0   = (rem & 7) * PBN;

    const unsigned short* X = wsin + XOFF + (size_t)t * QKV_ELEMS;  // [m][k] bf16
    const unsigned short* W = wsin + WOFF + (size_t)t * WSEG;       // [n][k] bf16
    const float* bias = (t == 0) ? bq : (t == 1) ? bk : bv;
    unsigned short* out = wsout + (size_t)t * QKV_ELEMS;
    const float scale = (t == 0) ? QSCALE : 1.0f;

    // [128 rows][32 bf16] linear, 64B rows; dbuf
    __shared__ __align__(16) unsigned short Abuf[2][PBM * PBK];
    __shared__ __align__(16) unsigned short Bbuf[2][PBN * PBK];

    const int tid  = threadIdx.x;
    const int wave = tid >> 6;
    const int lane = tid & 63;
    const int lrow = lane & 15;
    const int lg   = lane >> 4;
    const int wr = (wave >> 1) * 64;
    const int wc = (wave & 1) * 64;

    f32x4 acc[4][4];
#pragma unroll
    for (int i = 0; i < 4; ++i)
#pragma unroll
        for (int j = 0; j < 4; ++j)
            acc[i][j] = (f32x4){0.f, 0.f, 0.f, 0.f};

    // staging coords: issue i0 covers rows [i0*64, i0*64+64); thread -> (row, chunk)
    const int srow_ = tid >> 2;          // 0..63
    const int sc_   = tid & 3;           // 16B chunk
    // read-side swizzled chunk (row&3 == lrow&3 for fragment rows)
    const int gsw = (lg ^ (lrow & 3)) * 8;

    // prologue: stage k0 = 0 into buf 0
#pragma unroll
    for (int i0 = 0; i0 < 2; ++i0) {
        const int row = i0 * 64 + srow_;
        const int c   = sc_ ^ (row & 3);
        gload_lds16(X + (size_t)(m0 + row) * DMODEL + c * 8, &Abuf[0][i0 * 2048 + tid * 8]);
        gload_lds16(W + (size_t)(n0 + row) * DMODEL + c * 8, &Bbuf[0][i0 * 2048 + tid * 8]);
    }
    __syncthreads();

    int cur = 0;
    for (int k0 = 0; k0 < DMODEL; k0 += PBK) {
        if (k0 + PBK < DMODEL) {
#pragma unroll
            for (int i0 = 0; i0 < 2; ++i0) {
                const int row = i0 * 64 + srow_;
                const int c   = sc_ ^ (row & 3);
                gload_lds16(X + (size_t)(m0 + row) * DMODEL + k0 + PBK + c * 8,
                            &Abuf[cur ^ 1][i0 * 2048 + tid * 8]);
                gload_lds16(W + (size_t)(n0 + row) * DMODEL + k0 + PBK + c * 8,
                            &Bbuf[cur ^ 1][i0 * 2048 + tid * 8]);
            }
        }

        bf16x8 af[4], bw[4];
#pragma unroll
        for (int i = 0; i < 4; ++i) {
            af[i] = *(const bf16x8*)&Abuf[cur][(wr + i * 16 + lrow) * PBK + gsw];
            bw[i] = *(const bf16x8*)&Bbuf[cur][(wc + i * 16 + lrow) * PBK + gsw];
        }
        __builtin_amdgcn_s_setprio(1);
#pragma unroll
        for (int i = 0; i < 4; ++i)
#pragma unroll
            for (int j = 0; j < 4; ++j)
                acc[i][j] = __builtin_amdgcn_mfma_f32_16x16x32_bf16(af[i], bw[j], acc[i][j], 0, 0, 0);
        __builtin_amdgcn_s_setprio(0);

        __syncthreads();   // drains staged loads; next iter reads buf[cur^1]
        cur ^= 1;
    }

#pragma unroll
    for (int j = 0; j < 4; ++j) {
        const int n  = n0 + wc + j * 16 + lrow;
        const float bv_ = bias[n];
        const int h  = n >> 6;
        const int dd = n & 63;
#pragma unroll
        for (int i = 0; i < 4; ++i) {
#pragma unroll
            for (int r = 0; r < 4; ++r) {
                const int m = m0 + wr + i * 16 + lg * 4 + r;
                const int s = m >> 1;
                const int b = m & 1;
                const float v = (acc[i][j][r] + bv_) * scale;
                size_t idx;
                if (t == 2)
                    idx = ((size_t)((b * NHEAD + h) * HDIM + dd)) * S_LEN + s;
                else
                    idx = ((size_t)((b * NHEAD + h) * S_LEN + s)) * HDIM + dd;
                out[idx] = f2bf(v);
            }
        }
    }
}

// ---------------------------------------------------------------------------
// Flash attention (unchanged from R11 — 16 q/wave 16x16x32, 4096 waves,
// verified ~56 us): dbuf gload_lds, in-reg softmax, defer-max, ones-MFMA sum.
// ---------------------------------------------------------------------------
#define NT (S_LEN / 64)
#define PUSTR 17

__global__ __launch_bounds__(512, 4) void attn_kernel(
        const unsigned short* __restrict__ ws, float* __restrict__ out)
{
    const unsigned short* Qw = ws;
    const unsigned short* Kw = ws + QKV_ELEMS;
    const unsigned short* Vw = ws + 2 * QKV_ELEMS;   // [b][h][d][s]

    const int bid = blockIdx.x;
    const int idx = bid >> 3;                        // 0..63
    const int bh  = (bid & 7) * 4 + (idx >> 4);      // 0..31
    const int q0  = (idx & 15) * 128;

    __shared__ __align__(16) unsigned short Kbuf[2][64 * 64];
    __shared__ __align__(16) unsigned short Vbuf[2][64 * 64];
    __shared__ unsigned int Pu[8][32 * PUSTR];

    const int tid  = threadIdx.x;
    const int wave = tid >> 6;
    const int lane = tid & 63;
    const int lrow = lane & 15;
    const int lg   = lane >> 4;

    const size_t base = (size_t)bh * S_LEN * HDIM;
    const int qrow = q0 + wave * 16 + lrow;

    bf16x8 qf[2];
#pragma unroll
    for (int c = 0; c < 2; ++c)
        qf[c] = *(const bf16x8*)(Qw + base + (size_t)qrow * HDIM + c * 32 + lg * 8);

    bf16x8 ones;
    {
        u16x8 o;
#pragma unroll
        for (int e = 0; e < 8; ++e) o[e] = 0x3F80;
        ones = __builtin_bit_cast(bf16x8, o);
    }

    f32x4 O[4], Lacc;
#pragma unroll
    for (int dt = 0; dt < 4; ++dt) O[dt] = (f32x4){0.f, 0.f, 0.f, 0.f};
    Lacc = (f32x4){0.f, 0.f, 0.f, 0.f};
    float mrun = -__builtin_inff();

    const int srow = tid >> 3;                 // 0..63
    const int sgrp = (tid & 7) ^ (srow & 7);   // XOR-swizzled source group
    const int dsto = tid * 8;

    gload_lds16(Kw + base + (size_t)srow * HDIM + sgrp * 8,  &Kbuf[0][dsto]);
    gload_lds16(Vw + base + (size_t)srow * S_LEN + sgrp * 8, &Vbuf[0][dsto]);
    __syncthreads();

    int cur = 0;
    for (int t = 0; t < NT; ++t) {
        if (t + 1 < NT) {
            const int sn = (t + 1) * 64;
            gload_lds16(Kw + base + (size_t)(sn + srow) * HDIM + sgrp * 8, &Kbuf[cur ^ 1][dsto]);
            gload_lds16(Vw + base + (size_t)srow * S_LEN + sn + sgrp * 8, &Vbuf[cur ^ 1][dsto]);
        }

        const unsigned short* Klds = Kbuf[cur];
        const unsigned short* Vlds = Vbuf[cur];

        f32x4 S[4];
#pragma unroll
        for (int kt = 0; kt < 4; ++kt) S[kt] = (f32x4){0.f, 0.f, 0.f, 0.f};
        __builtin_amdgcn_s_setprio(1);
#pragma unroll
        for (int kt = 0; kt < 4; ++kt) {
#pragma unroll
            for (int c = 0; c < 2; ++c) {
                const int g = ((c * 4 + lg) ^ (lrow & 7)) * 8;
                const bf16x8 ka = *(const bf16x8*)&Klds[(kt * 16 + lrow) * 64 + g];
                S[kt] = __builtin_amdgcn_mfma_f32_16x16x32_bf16(ka, qf[c], S[kt], 0, 0, 0);
            }
        }
        __builtin_amdgcn_s_setprio(0);

        float m0_ = fmaxf(fmaxf(S[0][0], S[0][1]), fmaxf(S[0][2], S[0][3]));
        float m1_ = fmaxf(fmaxf(S[1][0], S[1][1]), fmaxf(S[1][2], S[1][3]));
        float m2_ = fmaxf(fmaxf(S[2][0], S[2][1]), fmaxf(S[2][2], S[2][3]));
        float m3_ = fmaxf(fmaxf(S[3][0], S[3][1]), fmaxf(S[3][2], S[3][3]));
        float mx = fmaxf(fmaxf(m0_, m1_), fmaxf(m2_, m3_));
        mx = fmaxf(mx, __shfl_xor(mx, 16, 64));
        mx = fmaxf(mx, __shfl_xor(mx, 32, 64));

        if (!__all(mx - mrun <= 8.0f)) {
            const float mnew = fmaxf(mrun, mx);
            const float ex   = exp2f(mrun - mnew);
            mrun = mnew;
#pragma unroll
            for (int dt = 0; dt < 4; ++dt) O[dt] *= ex;
            Lacc *= ex;
        }

#pragma unroll
        for (int kt = 0; kt < 4; ++kt)
#pragma unroll
            for (int r = 0; r < 4; ++r)
                S[kt][r] = exp2f(S[kt][r] - mrun);

#pragma unroll
        for (int kt = 0; kt < 4; ++kt) {
#pragma unroll
            for (int i = 0; i < 2; ++i) {
                const unsigned int dw = pack2(S[kt][2 * i], S[kt][2 * i + 1]);
                const int kp = kt * 8 + lg * 2 + i;
                Pu[wave][kp * PUSTR + lrow] = dw;
            }
        }
        __asm__ volatile("" ::: "memory");

        __builtin_amdgcn_s_setprio(1);
        bf16x8 pb[2];
#pragma unroll
        for (int c = 0; c < 2; ++c) {
            u32x4 pu;
#pragma unroll
            for (int e = 0; e < 4; ++e)
                pu[e] = Pu[wave][(c * 16 + lg * 4 + e) * PUSTR + lrow];
            pb[c] = __builtin_bit_cast(bf16x8, pu);
        }
#pragma unroll
        for (int dt = 0; dt < 4; ++dt) {
#pragma unroll
            for (int c = 0; c < 2; ++c) {
                const int g = ((c * 4 + lg) ^ (lrow & 7)) * 8;
                const bf16x8 va = *(const bf16x8*)&Vlds[(dt * 16 + lrow) * 64 + g];
                O[dt] = __builtin_amdgcn_mfma_f32_16x16x32_bf16(va, pb[c], O[dt], 0, 0, 0);
            }
        }
        Lacc = __builtin_amdgcn_mfma_f32_16x16x32_bf16(ones, pb[0], Lacc, 0, 0, 0);
        Lacc = __builtin_amdgcn_mfma_f32_16x16x32_bf16(ones, pb[1], Lacc, 0, 0, 0);
        __builtin_amdgcn_s_setprio(0);

        __syncthreads();
        cur ^= 1;
    }

    const int bb = bh >> 4;
    const int hh = bh & 15;
    const float inv = 1.0f / Lacc[0];
    float* op = out + (size_t)qrow * (BATCH * DMODEL) + bb * DMODEL + hh * HDIM;
#pragma unroll
    for (int dt = 0; dt < 4; ++dt) {
        float4 v;
        v.x = O[dt][0] * inv; v.y = O[dt][1] * inv;
        v.z = O[dt][2] * inv; v.w = O[dt][3] * inv;
        *(float4*)(op + dt * 16 + lg * 4) = v;
    }
}

extern "C" void kernel_launch(void* const* d_in, const int* in_sizes, int n_in,
                              void* d_out, int out_size, void* d_ws, size_t ws_size,
                              hipStream_t stream) {
    const float* q  = (const float*)d_in[0];
    const float* k  = (const float*)d_in[1];
    const float* v  = (const float*)d_in[2];
    const float* Wq = (const float*)d_in[3];
    const float* bq = (const float*)d_in[4];
    const float* Wk = (const float*)d_in[5];
    const float* bk = (const float*)d_in[6];
    const float* Wv = (const float*)d_in[7];
    const float* bv = (const float*)d_in[8];
    unsigned short* ws = (unsigned short*)d_ws;
    float* out = (float*)d_out;

    cvt_kernel<<<dim3(1024, 6), dim3(256), 0, stream>>>(q, k, v, Wq, Wk, Wv, ws);
    proj_kernel<<<dim3(768), dim3(256), 0, stream>>>(ws, bq, bk, bv, ws);
    attn_kernel<<<dim3(512), dim3(512), 0, stream>>>(ws, out);
}